// Round 2
// baseline (551.477 us; speedup 1.0000x reference)
//
#include <hip/hip_runtime.h>
#include <hip/hip_bf16.h>
#include <stdint.h>

#define TOKENS 8192
#define DIN 4096
#define DOUT 4096
#define RNK 16
#define LORA_SCALE 2.0f

typedef __attribute__((ext_vector_type(8))) __bf16 bf16x8;
typedef __attribute__((ext_vector_type(4))) float f32x4;

__device__ __forceinline__ unsigned short f2bf(float f) {
    union { float f; unsigned int u; } v; v.f = f;
    unsigned int u = v.u;
    unsigned int r = (u + 0x7fffu + ((u >> 16) & 1u)) >> 16;  // RNE
    return (unsigned short)r;
}

__device__ __forceinline__ void async_copy16(const void* g, void* l) {
    __builtin_amdgcn_global_load_lds(
        (const __attribute__((address_space(1))) void*)g,
        (__attribute__((address_space(3))) void*)l,
        16, 0, 0);
}

// ---------------- kernel 1: fused prep ----------------
// blocks [0, CAST_BLOCKS): cast x fp32 -> bf16
// blocks [CAST_BLOCKS, +FOLD_BLOCKS): W' = bf16(W + 2 * B @ A)
#define CAST_BLOCKS (TOKENS * DIN / 4 / 256)          // 32768
#define FOLD_BLOCKS ((DIN / (256 * 4)) * DOUT)        // 16384

__global__ void prep_kernel(const float4* __restrict__ x, ushort4* __restrict__ xb,
                            const float* __restrict__ W,
                            const float* __restrict__ lA,
                            const float* __restrict__ lB,
                            ushort* __restrict__ Wb) {
    __shared__ float sB[RNK];
    const int b = blockIdx.x;
    if (b < CAST_BLOCKS) {
        int i = b * 256 + threadIdx.x;
        float4 v = x[i];
        ushort4 o;
        o.x = f2bf(v.x); o.y = f2bf(v.y); o.z = f2bf(v.z); o.w = f2bf(v.w);
        xb[i] = o;
    } else {
        const int bb = b - CAST_BLOCKS;
        const int o  = bb >> 2;
        const int i0 = ((bb & 3) * 256 + threadIdx.x) * 4;
        if (threadIdx.x < RNK) sB[threadIdx.x] = lB[(size_t)o * RNK + threadIdx.x];
        __syncthreads();
        float4 w = *(const float4*)(W + (size_t)o * DIN + i0);
        float ax = 0.f, ay = 0.f, az = 0.f, aw = 0.f;
#pragma unroll
        for (int r = 0; r < RNK; r++) {
            float4 a = *(const float4*)(lA + (size_t)r * DIN + i0);
            float bv = sB[r];
            ax += bv * a.x; ay += bv * a.y; az += bv * a.z; aw += bv * a.w;
        }
        ushort4 outv;
        outv.x = f2bf(w.x + LORA_SCALE * ax);
        outv.y = f2bf(w.y + LORA_SCALE * ay);
        outv.z = f2bf(w.z + LORA_SCALE * az);
        outv.w = f2bf(w.w + LORA_SCALE * aw);
        *(ushort4*)(Wb + (size_t)o * DIN + i0) = outv;
    }
}

// ---------------- kernel 2: Y = Xb @ Wb^T + bias ----------------
// 256x256 tile, BK=32, 4-slot LDS ring (128 KiB).
// Pipeline v2: fragment ds_reads are issued one MFMA-cluster AHEAD so the
// LDS pipe drains under the MFMA clusters (m196: the fine interleave is the
// lever). Compiler emits the counted lgkmcnt. One barrier per K-tile; counted
// vmcnt(4) at the boundary (never 0 mid-loop). Stage 3 tiles ahead.
//
// Ring safety (1 barrier/region): concurrent waves are all inside region t.
// Region t ISSUES writes to slot (t+3)&3 == (t-1)&3; READS slots t&3 (p1
// frags) and (t+1)&3 (next-tile frags) -> disjoint. Writes issued in region
// t land before end of region t+1 (vmcnt(4)); first read of that slot is in
// region t+2, after the barrier. Reads of tile u issued in region u-1 need
// tile u landed: boundary of region u-2 waits vmcnt(4) -> tile u landed.
#define BM 256
#define BN 256
#define BK 32
#define NTILES (DIN / BK)      // 128
#define SLOT_U16 16384         // A 8192 + B 8192 ushorts = 32 KB
#define SLOT_BYTES 32768
#define B_OFF_BYTES 16384

__global__ __launch_bounds__(512, 2) void gemm_bias_kernel(
    const ushort* __restrict__ Xb, const ushort* __restrict__ Wb,
    const float* __restrict__ bias, float* __restrict__ Y) {

    __shared__ ushort smem[4 * SLOT_U16];   // 128 KiB ring

    const int tid  = threadIdx.x;
    const int lane = tid & 63;
    const int wave = tid >> 6;

    // XCD-bijective swizzle: 512 wgs, 8 XCDs, 64 contiguous tiles per XCD.
    const int bid  = blockIdx.x;
    const int sbid = (bid & 7) * 64 + (bid >> 3);
    const int m0 = (sbid >> 4) * BM;
    const int n0 = (sbid & 15) * BN;

    const int wm = (wave >> 2) * 128;       // 2 M-wave-groups
    const int wn = (wave & 3) * 64;         // 4 N-wave-groups

    // staging source addresses (inverse of the LDS chunk swizzle; m173 pattern)
    auto srcoff = [](int ci) -> size_t {
        const int L = ci >> 3, p = ci & 7;
        const int u = p ^ (L & 7);
        return (size_t)(2 * L + (u >> 2)) * DIN + (size_t)((u & 3) * 8);
    };
    const ushort* pA0 = Xb + (size_t)m0 * DIN + srcoff(tid);
    const ushort* pA1 = Xb + (size_t)m0 * DIN + srcoff(tid + 512);
    const ushort* pB0 = Wb + (size_t)n0 * DIN + srcoff(tid);
    const ushort* pB1 = Wb + (size_t)n0 * DIN + srcoff(tid + 512);

#define STAGE_A(slot) do { \
        ushort* d_ = smem + (slot) * SLOT_U16 + tid * 8; \
        async_copy16(pA0, d_); async_copy16(pA1, d_ + 4096); \
        pA0 += BK; pA1 += BK; } while (0)
#define STAGE_B(slot) do { \
        ushort* d_ = smem + (slot) * SLOT_U16 + 8192 + tid * 8; \
        async_copy16(pB0, d_); async_copy16(pB1, d_ + 4096); \
        pB0 += BK; pB1 += BK; } while (0)

    // fragment-read byte offsets (swizzle-aware), constant per lane
    const int lr = lane & 15, qq = lane >> 4;
    const int pp = (qq + 4 * (lr & 1)) ^ ((lr >> 1) & 7);
    const int offA = ((wm >> 1) + (lr >> 1)) * 128 + pp * 16;
    const int offB = B_OFF_BYTES + ((wn >> 1) + (lr >> 1)) * 128 + pp * 16;
    const char* smemc = (const char*)smem;

    f32x4 acc[8][4] = {};
    bf16x8 af[4], af2[4], bfr[4];

    // prologue: stage tiles 0,1,2; wait until tiles 0,1 landed (tile 2 in flight)
    STAGE_A(0); STAGE_B(0);
    STAGE_A(1); STAGE_B(1);
    STAGE_A(2); STAGE_B(2);
    asm volatile("s_waitcnt vmcnt(4)" ::: "memory");
    __builtin_amdgcn_s_barrier();

    // tile-0 p0 fragments
#pragma unroll
    for (int f = 0; f < 4; f++) af[f]  = *(const bf16x8*)(smemc + offA + f * 1024);
#pragma unroll
    for (int f = 0; f < 4; f++) bfr[f] = *(const bf16x8*)(smemc + offB + f * 1024);

#pragma unroll 1
    for (int t = 0; t < NTILES; ++t) {
        const char* sa  = smemc + (size_t)(t & 3) * SLOT_BYTES;
        const char* saN = smemc + (size_t)((t + 1) & 3) * SLOT_BYTES;
        const int  stslot  = (t + 3) & 3;
        const bool doStage = (t + 3 < NTILES);
        const bool haveNext = (t + 1 < NTILES);

        // ---- phase 0: issue p1 A-frag reads, stage A, MFMA p0 ----
#pragma unroll
        for (int f = 0; f < 4; f++)
            af2[f] = *(const bf16x8*)(sa + offA + (4 + f) * 1024);
        if (doStage) STAGE_A(stslot);
        __builtin_amdgcn_s_setprio(1);
#pragma unroll
        for (int mf = 0; mf < 4; mf++)
#pragma unroll
            for (int nf = 0; nf < 4; nf++)
                acc[mf][nf] = __builtin_amdgcn_mfma_f32_16x16x32_bf16(
                    af[mf], bfr[nf], acc[mf][nf], 0, 0, 0);
        __builtin_amdgcn_s_setprio(0);

        // ---- phase 1: issue next-tile A-frag reads, stage B, MFMA p1 ----
        if (haveNext) {
#pragma unroll
            for (int f = 0; f < 4; f++)
                af[f] = *(const bf16x8*)(saN + offA + f * 1024);
        }
        if (doStage) STAGE_B(stslot);
        __builtin_amdgcn_s_setprio(1);
#pragma unroll
        for (int mf = 0; mf < 4; mf++)
#pragma unroll
            for (int nf = 0; nf < 4; nf++)
                acc[4 + mf][nf] = __builtin_amdgcn_mfma_f32_16x16x32_bf16(
                    af2[mf], bfr[nf], acc[4 + mf][nf], 0, 0, 0);
        __builtin_amdgcn_s_setprio(0);

        // ---- tail: issue next-tile B-frag reads (drain under boundary sync) ----
        if (haveNext) {
#pragma unroll
            for (int f = 0; f < 4; f++)
                bfr[f] = *(const bf16x8*)(saN + offB + f * 1024);
        }

        // ---- boundary: counted vmcnt + single barrier per tile ----
        if (t < NTILES - 3) {
            asm volatile("s_waitcnt vmcnt(4)" ::: "memory");
            __builtin_amdgcn_s_barrier();
        } else if (t == NTILES - 3) {
            asm volatile("s_waitcnt vmcnt(0)" ::: "memory");
            __builtin_amdgcn_s_barrier();
        }
        // t >= NTILES-2: no LDS writes remain anywhere -> no sync needed
    }

    // epilogue: C/D layout col=lane&15, row=(lane>>4)*4+reg [m89/m91]
    const int col  = lane & 15;
    const int qrow = (lane >> 4) * 4;
#pragma unroll
    for (int nf = 0; nf < 4; nf++) {
        const int n = n0 + wn + nf * 16 + col;
        const float bv = bias[n];
#pragma unroll
        for (int mf = 0; mf < 8; mf++) {
            const int m = m0 + wm + mf * 16 + qrow;
            float* yp = Y + (size_t)m * DOUT + n;
            yp[0]                  = acc[mf][nf].x + bv;
            yp[(size_t)DOUT]       = acc[mf][nf].y + bv;
            yp[2 * (size_t)DOUT]   = acc[mf][nf].z + bv;
            yp[3 * (size_t)DOUT]   = acc[mf][nf].w + bv;
        }
    }
#undef STAGE_A
#undef STAGE_B
}

extern "C" void kernel_launch(void* const* d_in, const int* in_sizes, int n_in,
                              void* d_out, int out_size, void* d_ws, size_t ws_size,
                              hipStream_t stream) {
    const float* x    = (const float*)d_in[0];
    const float* W    = (const float*)d_in[1];
    const float* bias = (const float*)d_in[2];
    const float* lA   = (const float*)d_in[3];
    const float* lB   = (const float*)d_in[4];
    float* Y = (float*)d_out;

    ushort* xb = (ushort*)d_ws;                       // 64 MB
    ushort* wb = xb + (size_t)TOKENS * DIN;           // +32 MB

    prep_kernel<<<CAST_BLOCKS + FOLD_BLOCKS, 256, 0, stream>>>(
        (const float4*)x, (ushort4*)xb, W, lA, lB, wb);
    gemm_bias_kernel<<<dim3((TOKENS / BM) * (DOUT / BN)), 512, 0, stream>>>(
        xb, wb, bias, Y);
}